// Round 7
// baseline (583.854 us; speedup 1.0000x reference)
//
#include <hip/hip_runtime.h>
#include <hip/hip_bf16.h>
#include <cstddef>

// GCN: h0 = relu(spmm(x@W0^T)); h1 = relu(spmm(h0@W1^T)); out = spmm(h1@W2^T)
// R13: (a) UN-merge R12's d2 (hist8 blocks inherited GEMM0's 36KB-LDS/120-VGPR
// footprint -> 4 blocks/CU occupancy cap -> 132us; separate kernels restore
// hist8's high occupancy). (b) Edge-descriptor double-buffering in all gather
// loops: batch b+1's descriptor loads issue before batch b's gathers are
// consumed, overlapping desc latency with gather+VALU (the desc stream proved
// expensive: R12's 4B packing saved ~130us). fp8 activations + 4B packed es
// + atomic-free scatter retained.

typedef unsigned short ushort_t;
typedef unsigned char u8;
using frag_t = __attribute__((ext_vector_type(8))) short;   // 8 bf16
using accf4 = __attribute__((ext_vector_type(4))) float;    // 4 fp32

__device__ __forceinline__ ushort_t f2bf(float f) {
    unsigned int u = __float_as_uint(f);
    u += 0x7FFF + ((u >> 16) & 1);   // RNE
    return (ushort_t)(u >> 16);
}
__device__ __forceinline__ float bf2f(unsigned int u16) {
    return __uint_as_float(u16 << 16);
}
__device__ __forceinline__ u8 f2fp8(float a) {
    return (u8)(__builtin_amdgcn_cvt_pk_fp8_f32(a, 0.f, 0, false) & 0xff);
}
// decode 4 packed fp8 -> acc[0..3] += v * val
__device__ __forceinline__ void acc4_fp8(float* acc, unsigned q, float v) {
    auto p0 = __builtin_amdgcn_cvt_pk_f32_fp8((int)q, false);
    auto p1 = __builtin_amdgcn_cvt_pk_f32_fp8((int)q, true);
    acc[0] += v * p0[0]; acc[1] += v * p0[1];
    acc[2] += v * p1[0]; acc[3] += v * p1[1];
}
__device__ __forceinline__ void acc8_fp8(float* acc, uint2 q, float v) {
    acc4_fp8(acc, q.x, v);
    acc4_fp8(acc + 4, q.y, v);
}

// ---------------- init: zero slice counters + convert W1/W2 ----------------

__global__ __launch_bounds__(256) void init0_k(int* __restrict__ cnt8, int m8,
                                               const float* __restrict__ W1,
                                               const float* __restrict__ W2,
                                               ushort_t* __restrict__ Wb1,
                                               ushort_t* __restrict__ Wb2) {
    int i = blockIdx.x * 256 + threadIdx.x;
    if (i < m8) cnt8[i] = 0;
    if (i < 16384) Wb1[i] = f2bf(W1[i]);
    else if (i < 24576) Wb2[i - 16384] = f2bf(W2[i - 16384]);
}

// ---------------- GEMM0: C[M,128] = A[M,512](f32) * W[128,512](f32)^T -------
// fp8 output (g0 is edge-gathered downstream). Standalone dispatch.

__global__ __launch_bounds__(256) void gemm0_k(const float* __restrict__ A,
                                               const float* __restrict__ W,
                                               u8* __restrict__ C, int M) {
    constexpr int K = 512, N = 128, BM = 128, BN = 128, BK = 64;
    constexpr int WM = BM / 2, WN = BN / 2;
    constexpr int TI = WM / 16, TJ = WN / 16;
    constexpr int LDA = BK + 8;
    constexpr int T = K / BK;
    constexpr int A_PER = BM * BK / 4 / 256;   // 8 float4 per thread
    constexpr int B_PER = BN * BK / 4 / 256;   // 8 float4 per thread

    __shared__ __align__(16) ushort_t As[BM][LDA];
    __shared__ __align__(16) ushort_t Bs[BN][LDA];

    const int tid = threadIdx.x;
    const int lane = tid & 63;
    const int wid = tid >> 6;
    const int wm = wid >> 1, wn = wid & 1;
    const int rowBase = blockIdx.x * BM;
    const int lrow = lane & 15, kq = lane >> 4;

    float4 aF[A_PER], bF[B_PER];

    auto loadTile = [&](int k0) {
#pragma unroll
        for (int i = 0; i < A_PER; i++) {
            int idx = tid + i * 256;
            int r = idx / (BK / 4), c4 = idx % (BK / 4);
            int grow = rowBase + r;
            aF[i] = (grow < M) ? *(const float4*)(A + (size_t)grow * K + k0 + c4 * 4)
                               : make_float4(0.f, 0.f, 0.f, 0.f);
        }
#pragma unroll
        for (int i = 0; i < B_PER; i++) {
            int idx = tid + i * 256;
            int r = idx / (BK / 4), c4 = idx % (BK / 4);
            bF[i] = *(const float4*)(W + (size_t)r * K + k0 + c4 * 4);
        }
    };
    auto storeTile = [&]() {
#pragma unroll
        for (int i = 0; i < A_PER; i++) {
            int idx = tid + i * 256;
            int r = idx / (BK / 4), c4 = idx % (BK / 4);
            ushort_t p[4] = {f2bf(aF[i].x), f2bf(aF[i].y), f2bf(aF[i].z), f2bf(aF[i].w)};
            *(uint2*)&As[r][c4 * 4] = *(uint2*)p;
        }
#pragma unroll
        for (int i = 0; i < B_PER; i++) {
            int idx = tid + i * 256;
            int r = idx / (BK / 4), c4 = idx % (BK / 4);
            ushort_t p[4] = {f2bf(bF[i].x), f2bf(bF[i].y), f2bf(bF[i].z), f2bf(bF[i].w)};
            *(uint2*)&Bs[r][c4 * 4] = *(uint2*)p;
        }
    };

    accf4 acc[TI][TJ];
#pragma unroll
    for (int i = 0; i < TI; i++)
#pragma unroll
        for (int j = 0; j < TJ; j++) acc[i][j] = accf4{0.f, 0.f, 0.f, 0.f};

    loadTile(0);
    storeTile();
    __syncthreads();

    for (int t = 0; t < T; t++) {
        if (t + 1 < T) loadTile((t + 1) * BK);
#pragma unroll
        for (int ks = 0; ks < BK / 32; ks++) {
            const int kb = ks * 32 + kq * 8;
            frag_t a[TI], b[TJ];
#pragma unroll
            for (int i = 0; i < TI; i++)
                a[i] = *(const frag_t*)&As[wm * WM + i * 16 + lrow][kb];
#pragma unroll
            for (int j = 0; j < TJ; j++)
                b[j] = *(const frag_t*)&Bs[wn * WN + j * 16 + lrow][kb];
#pragma unroll
            for (int i = 0; i < TI; i++)
#pragma unroll
                for (int j = 0; j < TJ; j++)
                    acc[i][j] = __builtin_amdgcn_mfma_f32_16x16x32_bf16(
                        a[i], b[j], acc[i][j], 0, 0, 0);
        }
        __syncthreads();
        if (t + 1 < T) {
            storeTile();
            __syncthreads();
        }
    }

    // epilogue: C/D layout col=lane&15, row=(lane>>4)*4+reg; write fp8 bytes
#pragma unroll
    for (int i = 0; i < TI; i++) {
#pragma unroll
        for (int j = 0; j < TJ; j++) {
            int col = wn * WN + j * 16 + lrow;
#pragma unroll
            for (int r = 0; r < 4; r++) {
                int grow = rowBase + wm * WM + i * 16 + kq * 4 + r;
                if (grow < M) C[(size_t)grow * N + col] = f2fp8(acc[i][j][r]);
            }
        }
    }
}

// ---------------- XCD-local rank (standalone, high occupancy) ----------------

__global__ __launch_bounds__(256) void hist8_k(const int* __restrict__ rows,
                                               int* __restrict__ cnt8,
                                               int* __restrict__ rank,
                                               int n, int ne) {
    int e = blockIdx.x * 256 + threadIdx.x;
    if (e >= ne) return;
    int s = blockIdx.x & 7;                    // ~= XCD id (round-robin dispatch)
    rank[e] = atomicAdd(&cnt8[s * n + rows[e]], 1);
}

// ---------------- scan building blocks ----------------

// transposed block totals: element i of the scanned sequence is
// cnt8[(i&7)*n + (i>>3)] (row-major, slice-minor view)
__global__ __launch_bounds__(256) void block_totals_t(const int* __restrict__ cnt8,
                                                      int* __restrict__ bsums,
                                                      int n, int m8) {
    __shared__ int s[256];
    int t = threadIdx.x;
    int i = blockIdx.x * 256 + t;
    s[t] = (i < m8) ? cnt8[(i & 7) * n + (i >> 3)] : 0;
    __syncthreads();
    for (int off = 128; off > 0; off >>= 1) {
        if (t < off) s[t] += s[t + off];
        __syncthreads();
    }
    if (t == 0) bsums[blockIdx.x] = s[0];
}

// single block, 1024 threads, 4 elems/thread: exclusive scan of nb (<=4096)
// values in place.
__global__ __launch_bounds__(1024) void scan_mid(int* bsums, int nb) {
    __shared__ int s[1024];
    int t = threadIdx.x;
    int base = t * 4;
    int v0 = (base + 0 < nb) ? bsums[base + 0] : 0;
    int v1 = (base + 1 < nb) ? bsums[base + 1] : 0;
    int v2 = (base + 2 < nb) ? bsums[base + 2] : 0;
    int v3 = (base + 3 < nb) ? bsums[base + 3] : 0;
    int l0 = v0, l1 = l0 + v1, l2 = l1 + v2, l3 = l2 + v3;
    s[t] = l3;
    __syncthreads();
    for (int off = 1; off < 1024; off *= 2) {
        int u = (t >= off) ? s[t - off] : 0;
        __syncthreads();
        s[t] += u;
        __syncthreads();
    }
    int excl = s[t] - l3;
    if (base + 0 < nb) bsums[base + 0] = excl;
    if (base + 1 < nb) bsums[base + 1] = excl + l0;
    if (base + 2 < nb) bsums[base + 2] = excl + l1;
    if (base + 3 < nb) bsums[base + 3] = excl + l2;
}

// final scan over the slice-minor view of cnt8: element i=(r*8+s) reads
// cnt8[s*n+r]; writes dstbase[i], row_ptr[r] at s==0, and row_ptr[n]=ne.
__global__ __launch_bounds__(256) void scan_final(const int* __restrict__ cnt8,
                                                  const int* __restrict__ offs,
                                                  int* __restrict__ dstbase,
                                                  int* __restrict__ row_ptr,
                                                  int n, int ne, int m8) {
    __shared__ int s[256];
    int t = threadIdx.x;
    int i = blockIdx.x * 256 + t;
    int v = (i < m8) ? cnt8[(i & 7) * n + (i >> 3)] : 0;
    s[t] = v;
    __syncthreads();
    for (int off = 1; off < 256; off *= 2) {
        int u = (t >= off) ? s[t - off] : 0;
        __syncthreads();
        s[t] += u;
        __syncthreads();
    }
    int excl = s[t] - v + offs[blockIdx.x];
    if (i < m8) {
        dstbase[i] = excl;
        if ((i & 7) == 0) row_ptr[i >> 3] = excl;
    }
    if (i == 0) row_ptr[n] = ne;
}

// ---------------- atomic-free scatter (packed 4B edge) ----------------
// es[p] = (col << 14) | (bf16bits(val)); col < 2^17, val in [0,1) -> < 0x4000

__global__ __launch_bounds__(256) void scatter8_k(const int* __restrict__ rows,
                                                  const int* __restrict__ cols,
                                                  const float* __restrict__ vals,
                                                  const int* __restrict__ dstbase,
                                                  const int* __restrict__ rank,
                                                  unsigned* __restrict__ es, int ne) {
    int e = blockIdx.x * 256 + threadIdx.x;
    if (e >= ne) return;
    int s = blockIdx.x & 7;                    // must match hist8_k's mapping
    int r = rows[e];
    int p = dstbase[r * 8 + s] + rank[e];
    es[p] = ((unsigned)cols[e] << 14) | ((unsigned)f2bf(vals[e]) & 0x3fff);
}

// ---------------- fused SpMM + dense layer (fp8 gathers, packed es) ---------
// Descriptor double-buffer: batch b+1's es loads issue before batch b's
// gathers are consumed -> desc latency overlaps gather+VALU of prior batch.

__device__ __forceinline__ void gather_pair_128(const int* __restrict__ row_ptr,
                                                const unsigned* __restrict__ es,
                                                const u8* __restrict__ Gp,
                                                int rowA, int rowB, int n,
                                                int g, float* accA, float* accB) {
    int sA = 0, eA = 0, sB = 0, eB = 0;
    if (rowA < n) { sA = row_ptr[rowA]; eA = row_ptr[rowA + 1]; }
    if (rowB < n) { sB = row_ptr[rowB]; eB = row_ptr[rowB + 1]; }
    int nbA = (eA - sA + 15) >> 4, nbB = (eB - sB + 15) >> 4;
    int nb = nbA > nbB ? nbA : nbB;
    if (nb <= 0) return;

    unsigned edA[4], edB[4], nxA[4], nxB[4];
#pragma unroll
    for (int u = 0; u < 4; u++) {
        int ia = sA + u * 4 + g;
        edA[u] = (ia < eA) ? es[ia] : 0u;
        int ib = sB + u * 4 + g;
        edB[u] = (ib < eB) ? es[ib] : 0u;
    }
    for (int b = 0; b < nb; b++) {
        if (b + 1 < nb) {
#pragma unroll
            for (int u = 0; u < 4; u++) {
                int ia = sA + (b + 1) * 16 + u * 4 + g;
                nxA[u] = (ia < eA) ? es[ia] : 0u;
                int ib = sB + (b + 1) * 16 + u * 4 + g;
                nxB[u] = (ib < eB) ? es[ib] : 0u;
            }
        }
        uint2 qA[4], qB[4];
#pragma unroll
        for (int u = 0; u < 4; u++) {
            qA[u] = make_uint2(0, 0);
            if (edA[u] & 0x3fff) qA[u] = *(const uint2*)(Gp + (size_t)(edA[u] >> 14) * 128);
        }
#pragma unroll
        for (int u = 0; u < 4; u++) {
            qB[u] = make_uint2(0, 0);
            if (edB[u] & 0x3fff) qB[u] = *(const uint2*)(Gp + (size_t)(edB[u] >> 14) * 128);
        }
#pragma unroll
        for (int u = 0; u < 4; u++) acc8_fp8(accA, qA[u], bf2f(edA[u] & 0x3fff));
#pragma unroll
        for (int u = 0; u < 4; u++) acc8_fp8(accB, qB[u], bf2f(edB[u] & 0x3fff));
#pragma unroll
        for (int u = 0; u < 4; u++) { edA[u] = nxA[u]; edB[u] = nxB[u]; }
    }
}

template <int NOUT>   // 128 or 64
__global__ __launch_bounds__(256) void spmm_mfma(const int* __restrict__ row_ptr,
                                                 const unsigned* __restrict__ es,
                                                 const u8* __restrict__ G,
                                                 const ushort_t* __restrict__ Wb,
                                                 u8* __restrict__ Hout, int n) {
    constexpr int TJ = NOUT / 64;              // N-slice tiles per wave (2 or 1)
    constexpr int SEG = NOUT / 16;             // uint4 (16B) segments per row

    __shared__ __align__(16) ushort_t Hs[16][136];       // relu'd spmm rows (bf16)
    __shared__ __align__(16) u8 Os[16][NOUT + 16];       // staged fp8 output

    const int tid = threadIdx.x;
    const int lane = tid & 63;
    const int wid = tid >> 6;
    const int g = lane >> 4, lg = lane & 15;
    const int lrow = lane & 15, kq = lane >> 4;
    const int rowBase = blockIdx.x * 16;

    // ---- phase 1: 2 row-pairs per wave, interleaved fp8 gathers ----
    const u8* __restrict__ Gp = G + lg * 8;    // 8 fp8 values per lane
#pragma unroll
    for (int pr = 0; pr < 2; pr++) {
        int rowA = rowBase + wid * 4 + pr * 2;
        int rowB = rowA + 1;
        float accA[8], accB[8];
#pragma unroll
        for (int k = 0; k < 8; k++) { accA[k] = 0.f; accB[k] = 0.f; }
        gather_pair_128(row_ptr, es, Gp, rowA, rowB, n, g, accA, accB);
#pragma unroll
        for (int k = 0; k < 8; k++) {
            accA[k] += __shfl_xor(accA[k], 16);
            accA[k] += __shfl_xor(accA[k], 32);
            accB[k] += __shfl_xor(accB[k], 16);
            accB[k] += __shfl_xor(accB[k], 32);
        }
        if (g == 0) {
            uint4 o;
            o.x = (unsigned)f2bf(fmaxf(accA[0], 0.f)) | ((unsigned)f2bf(fmaxf(accA[1], 0.f)) << 16);
            o.y = (unsigned)f2bf(fmaxf(accA[2], 0.f)) | ((unsigned)f2bf(fmaxf(accA[3], 0.f)) << 16);
            o.z = (unsigned)f2bf(fmaxf(accA[4], 0.f)) | ((unsigned)f2bf(fmaxf(accA[5], 0.f)) << 16);
            o.w = (unsigned)f2bf(fmaxf(accA[6], 0.f)) | ((unsigned)f2bf(fmaxf(accA[7], 0.f)) << 16);
            *(uint4*)&Hs[wid * 4 + pr * 2][lg * 8] = o;
        }
        if (g == 1) {
            uint4 o;
            o.x = (unsigned)f2bf(fmaxf(accB[0], 0.f)) | ((unsigned)f2bf(fmaxf(accB[1], 0.f)) << 16);
            o.y = (unsigned)f2bf(fmaxf(accB[2], 0.f)) | ((unsigned)f2bf(fmaxf(accB[3], 0.f)) << 16);
            o.z = (unsigned)f2bf(fmaxf(accB[4], 0.f)) | ((unsigned)f2bf(fmaxf(accB[5], 0.f)) << 16);
            o.w = (unsigned)f2bf(fmaxf(accB[6], 0.f)) | ((unsigned)f2bf(fmaxf(accB[7], 0.f)) << 16);
            *(uint4*)&Hs[wid * 4 + pr * 2 + 1][lg * 8] = o;
        }
    }

    // W fragments for this wave's N-slice (loaded late to cap VGPR pressure)
    frag_t bfr[4][TJ];
#pragma unroll
    for (int ks = 0; ks < 4; ks++)
#pragma unroll
        for (int j = 0; j < TJ; j++)
            bfr[ks][j] = *(const frag_t*)&Wb[(size_t)(wid * 16 * TJ + j * 16 + lrow) * 128 +
                                             ks * 32 + kq * 8];
    __syncthreads();

    // ---- phase 2: MFMA 16 x 128 x NOUT ----
    accf4 oacc[TJ];
#pragma unroll
    for (int j = 0; j < TJ; j++) oacc[j] = accf4{0.f, 0.f, 0.f, 0.f};
#pragma unroll
    for (int ks = 0; ks < 4; ks++) {
        frag_t a = *(const frag_t*)&Hs[lrow][ks * 32 + kq * 8];
#pragma unroll
        for (int j = 0; j < TJ; j++)
            oacc[j] = __builtin_amdgcn_mfma_f32_16x16x32_bf16(a, bfr[ks][j], oacc[j], 0, 0, 0);
    }
#pragma unroll
    for (int j = 0; j < TJ; j++) {
        int col = wid * 16 * TJ + j * 16 + lrow;
#pragma unroll
        for (int r = 0; r < 4; r++) Os[kq * 4 + r][col] = f2fp8(oacc[j][r]);
    }
    __syncthreads();

    // ---- coalesced output: 16 rows x SEG uint4 segments ----
    if (tid < 16 * SEG) {
        int row16 = tid / SEG, sg = tid % SEG;
        if (rowBase + row16 < n)
            *(uint4*)&Hout[(size_t)(rowBase + row16) * NOUT + sg * 16] =
                *(const uint4*)&Os[row16][sg * 16];
    }
}

// ---------------- final SpMM: N=64 fp8 in, fp32 out, 2 rows/wave ------------

__global__ __launch_bounds__(256) void spmm_csr_64f(const int* __restrict__ row_ptr,
                                                    const unsigned* __restrict__ es,
                                                    const u8* __restrict__ G,
                                                    float* __restrict__ H, int n) {
    const int lane = threadIdx.x & 63;
    const int wid = threadIdx.x >> 6;
    const int g = lane >> 4, lg = lane & 15;
    const int rowA = blockIdx.x * 8 + wid * 2;
    const int rowB = rowA + 1;

    int sA = 0, eA = 0, sB = 0, eB = 0;
    if (rowA < n) { sA = row_ptr[rowA]; eA = row_ptr[rowA + 1]; }
    if (rowB < n) { sB = row_ptr[rowB]; eB = row_ptr[rowB + 1]; }
    int nbA = (eA - sA + 15) >> 4, nbB = (eB - sB + 15) >> 4;
    int nb = nbA > nbB ? nbA : nbB;

    float accA[4] = {0.f, 0.f, 0.f, 0.f}, accB[4] = {0.f, 0.f, 0.f, 0.f};
    const u8* __restrict__ Gp = G + lg * 4;    // 4 fp8 values per lane

    if (nb > 0) {
        unsigned edA[4], edB[4], nxA[4], nxB[4];
#pragma unroll
        for (int u = 0; u < 4; u++) {
            int ia = sA + u * 4 + g;
            edA[u] = (ia < eA) ? es[ia] : 0u;
            int ib = sB + u * 4 + g;
            edB[u] = (ib < eB) ? es[ib] : 0u;
        }
        for (int b = 0; b < nb; b++) {
            if (b + 1 < nb) {
#pragma unroll
                for (int u = 0; u < 4; u++) {
                    int ia = sA + (b + 1) * 16 + u * 4 + g;
                    nxA[u] = (ia < eA) ? es[ia] : 0u;
                    int ib = sB + (b + 1) * 16 + u * 4 + g;
                    nxB[u] = (ib < eB) ? es[ib] : 0u;
                }
            }
            unsigned qA[4], qB[4];
#pragma unroll
            for (int u = 0; u < 4; u++) {
                qA[u] = 0;
                if (edA[u] & 0x3fff) qA[u] = *(const unsigned*)(Gp + (size_t)(edA[u] >> 14) * 64);
            }
#pragma unroll
            for (int u = 0; u < 4; u++) {
                qB[u] = 0;
                if (edB[u] & 0x3fff) qB[u] = *(const unsigned*)(Gp + (size_t)(edB[u] >> 14) * 64);
            }
#pragma unroll
            for (int u = 0; u < 4; u++) acc4_fp8(accA, qA[u], bf2f(edA[u] & 0x3fff));
#pragma unroll
            for (int u = 0; u < 4; u++) acc4_fp8(accB, qB[u], bf2f(edB[u] & 0x3fff));
#pragma unroll
            for (int u = 0; u < 4; u++) { edA[u] = nxA[u]; edB[u] = nxB[u]; }
        }
    }
#pragma unroll
    for (int k = 0; k < 4; k++) {
        accA[k] += __shfl_xor(accA[k], 16);
        accA[k] += __shfl_xor(accA[k], 32);
        accB[k] += __shfl_xor(accB[k], 16);
        accB[k] += __shfl_xor(accB[k], 32);
    }
    if (g == 0 && rowA < n) {
        float4 o = make_float4(accA[0], accA[1], accA[2], accA[3]);
        *(float4*)(H + (size_t)rowA * 64 + lg * 4) = o;
    }
    if (g == 1 && rowB < n) {
        float4 o = make_float4(accB[0], accB[1], accB[2], accB[3]);
        *(float4*)(H + (size_t)rowB * 64 + lg * 4) = o;
    }
}

static inline size_t align_up(size_t x, size_t a) { return (x + a - 1) & ~(a - 1); }

extern "C" void kernel_launch(void* const* d_in, const int* in_sizes, int n_in,
                              void* d_out, int out_size, void* d_ws, size_t ws_size,
                              hipStream_t stream) {
    const float* x = (const float*)d_in[0];
    const int* rows = (const int*)d_in[1];
    const int* cols = (const int*)d_in[2];
    const float* vals = (const float*)d_in[3];
    const float* W0 = (const float*)d_in[4];
    const float* W1 = (const float*)d_in[5];
    const float* W2 = (const float*)d_in[6];
    float* out = (float*)d_out;

    const int IN = 512, HID = 128, OUT = 64;
    const int n = in_sizes[0] / IN;   // 100000
    const int ne = in_sizes[1];       // 1600000
    (void)OUT;

    // workspace carve-up
    char* ws = (char*)d_ws;
    size_t off = 0;
    u8* g0 = (u8*)(ws + off); off = align_up(off + (size_t)n * HID, 512);
    u8* g1 = (u8*)(ws + off); off = align_up(off + (size_t)n * HID, 512);
    u8* g2 = (u8*)(ws + off); off = align_up(off + (size_t)n * 64, 512);
    unsigned* es2 = (unsigned*)(ws + off); off = align_up(off + (size_t)ne * 4, 512);
    int* cnt8 = (int*)(ws + off); off = align_up(off + (size_t)8 * n * 4, 512);
    int* rank = (int*)(ws + off); off = align_up(off + (size_t)ne * 4, 512);
    int* dstbase = (int*)(ws + off); off = align_up(off + (size_t)8 * n * 4, 512);
    int* row_ptr = (int*)(ws + off); off = align_up(off + (size_t)(n + 1) * 4, 512);
    int* bsum0 = (int*)(ws + off); off = align_up(off + 4096 * 4, 512);
    ushort_t* Wb1 = (ushort_t*)(ws + off); off = align_up(off + (size_t)HID * HID * 2, 512);
    ushort_t* Wb2 = (ushort_t*)(ws + off); off = align_up(off + (size_t)64 * HID * 2, 512);

    const int eb = (ne + 255) / 256;       // 6250
    const int m8 = 8 * n;                  // 800000
    const int nb8 = (m8 + 255) / 256;      // 3125 (<= 4096 for scan_mid)
    const int gblocks = (n + 127) / 128;   // 782
    const int fblocks = (n + 15) / 16;     // 6250

    // ---- init (tiny): zero cnt8, convert W1/W2 ----
    init0_k<<<nb8, 256, 0, stream>>>(cnt8, m8, W1, W2, Wb1, Wb2);

    // ---- CSR build: standalone hist8 (high occupancy) ----
    hist8_k<<<eb, 256, 0, stream>>>(rows, cnt8, rank, n, ne);

    // ---- GEMM0 standalone (x @ W0^T, fp32 in, fp8 out) ----
    gemm0_k<<<gblocks, 256, 0, stream>>>(x, W0, g0, n);

    // ---- scans -> atomic-free scatter (4B packed edges) ----
    block_totals_t<<<nb8, 256, 0, stream>>>(cnt8, bsum0, n, m8);
    scan_mid<<<1, 1024, 0, stream>>>(bsum0, nb8);
    scan_final<<<nb8, 256, 0, stream>>>(cnt8, bsum0, dstbase, row_ptr, n, ne, m8);
    scatter8_k<<<eb, 256, 0, stream>>>(rows, cols, vals, dstbase, rank, es2, ne);

    // ---- fused layers ----
    spmm_mfma<128><<<fblocks, 256, 0, stream>>>(row_ptr, es2, g0, Wb1, g1, n);
    spmm_mfma<64><<<fblocks, 256, 0, stream>>>(row_ptr, es2, g1, Wb2, g2, n);
    spmm_csr_64f<<<(n + 7) / 8, 256, 0, stream>>>(row_ptr, es2, g2, out, n);
}